// Round 2
// baseline (750.822 us; speedup 1.0000x reference)
//
#include <hip/hip_runtime.h>

#define F_IN 64
#define NH 4
#define HC 128
#define NEG_SLOPE 0.2f
#define LN_EPS 1e-5f

// ---------------------------------------------------------------------------
// K0: detect whether edge_index arrived as int64 (little-endian) or int32.
// If int64 with values < 2^31 (N=50000), every odd int32 word in the first
// 2E words is a zero high-half. For int32 data these words are real indices.
// ---------------------------------------------------------------------------
__global__ void k0_detect(const int* __restrict__ ei, int E, int* __restrict__ flag) {
    __shared__ int any_nz;
    if (threadIdx.x == 0) any_nz = 0;
    __syncthreads();
    long long stride = (2LL * E) / 257;
    long long pos = (long long)(threadIdx.x + 1) * stride;
    int w = ei[pos | 1];                 // odd word index, < 2E
    if (w != 0) atomicOr(&any_nz, 1);
    __syncthreads();
    if (threadIdx.x == 0) flag[0] = (any_nz == 0) ? 1 : 0;   // 1 => int64
}

__device__ inline void load_edge(const int* __restrict__ ei, int E, int idx,
                                 int is64, int& s, int& d) {
    if (is64) { s = ei[2 * idx]; d = ei[2 * (E + idx)]; }   // low words of int64
    else      { s = ei[idx];     d = ei[E + idx]; }
}

// ---------------------------------------------------------------------------
// K1: per-node h = x @ W (f32), plus a_src[n,h] = <h[n,h,:], att_src[h,:]>
// block = 128 (one thread per output channel), grid = N
// ---------------------------------------------------------------------------
__global__ __launch_bounds__(128) void k1_node_gemm(
    const float* __restrict__ x, const float* __restrict__ W,
    const float* __restrict__ att_src, const float* __restrict__ att_dst,
    float* __restrict__ h, float* __restrict__ a_src, float* __restrict__ a_dst)
{
    int node = blockIdx.x;
    int j = threadIdx.x;                 // 0..127
    __shared__ float xs[F_IN];
    if (j < F_IN) xs[j] = x[node * F_IN + j];
    __syncthreads();

    float acc = 0.f;
#pragma unroll 8
    for (int k = 0; k < F_IN; ++k)
        acc += xs[k] * W[k * HC + j];

    h[node * HC + j] = acc;

    int head = j >> 5;
    float vs = acc * att_src[j];         // att_* are [H,C] flat = HC
    float vd = acc * att_dst[j];
#pragma unroll
    for (int off = 16; off > 0; off >>= 1) {
        vs += __shfl_down(vs, off, 32);  // reduce within one head (32 lanes)
        vd += __shfl_down(vd, off, 32);
    }
    if ((j & 31) == 0) {
        a_src[node * NH + head] = vs;
        a_dst[node * NH + head] = vd;
    }
}

// ---------------------------------------------------------------------------
// K2: softmax denominator per (dst, head). No max-subtraction needed:
// exp(e)/sum(exp(e)) is invariant and |e| is O(10) here.
// ---------------------------------------------------------------------------
__global__ __launch_bounds__(256) void k2_denom(
    const int* __restrict__ ei, int E, int n, const int* __restrict__ flag,
    const float* __restrict__ a_src, const float* __restrict__ a_dst,
    float* __restrict__ denom)
{
    int idx = blockIdx.x * blockDim.x + threadIdx.x;
    int Etot = E + n;
    if (idx >= Etot) return;
    int is64 = flag[0];
    int s, d;
    if (idx < E) load_edge(ei, E, idx, is64, s, d);
    else         s = d = idx - E;
#pragma unroll
    for (int hh = 0; hh < NH; ++hh) {
        float e = a_src[s * NH + hh] + a_dst[d * NH + hh];
        e = (e >= 0.f) ? e : NEG_SLOPE * e;
        atomicAdd(&denom[d * NH + hh], __expf(e));
    }
}

// ---------------------------------------------------------------------------
// K3: message scatter. One thread per (edge, channel).
// ---------------------------------------------------------------------------
__global__ __launch_bounds__(256) void k3_message(
    const int* __restrict__ ei, int E, int n, const int* __restrict__ flag,
    const float* __restrict__ a_src, const float* __restrict__ a_dst,
    const float* __restrict__ denom, const float* __restrict__ h,
    float* __restrict__ accum)
{
    long long gid = (long long)blockIdx.x * blockDim.x + threadIdx.x;
    long long total = ((long long)E + n) * HC;
    if (gid >= total) return;
    int edge = (int)(gid >> 7);
    int ch   = (int)(gid & 127);
    int is64 = flag[0];
    int s, d;
    if (edge < E) load_edge(ei, E, edge, is64, s, d);
    else          s = d = edge - E;
    int head = ch >> 5;
    float e = a_src[s * NH + head] + a_dst[d * NH + head];
    e = (e >= 0.f) ? e : NEG_SLOPE * e;
    float alpha = __expf(e) / denom[d * NH + head];
    atomicAdd(&accum[d * HC + ch], h[s * HC + ch] * alpha);
}

// ---------------------------------------------------------------------------
// K4: epilogue per node: +bias, ELU, +(x@res_w + res_b), LayerNorm, f32 out
// ---------------------------------------------------------------------------
__device__ inline float block_reduce_128(float v, float* red) {
#pragma unroll
    for (int off = 32; off > 0; off >>= 1) v += __shfl_down(v, off, 64);
    int lane = threadIdx.x & 63, wid = threadIdx.x >> 6;
    if (lane == 0) red[wid] = v;
    __syncthreads();
    float t = red[0] + red[1];
    __syncthreads();
    return t;
}

__global__ __launch_bounds__(128) void k4_final(
    const float* __restrict__ accum, const float* __restrict__ x,
    const float* __restrict__ res_w, const float* __restrict__ res_b,
    const float* __restrict__ bias, const float* __restrict__ ln_g,
    const float* __restrict__ ln_b, float* __restrict__ out)
{
    int node = blockIdx.x;
    int j = threadIdx.x;
    __shared__ float xs[F_IN];
    __shared__ float red[2];
    if (j < F_IN) xs[j] = x[node * F_IN + j];
    __syncthreads();

    float r = 0.f;
#pragma unroll 8
    for (int k = 0; k < F_IN; ++k)
        r += xs[k] * res_w[k * HC + j];

    float o = accum[node * HC + j] + bias[j];
    o = (o > 0.f) ? o : expm1f(o);       // ELU
    o += r + res_b[j];                   // residual linear

    float mean = block_reduce_128(o, red) * (1.f / HC);
    float diff = o - mean;
    float var = block_reduce_128(diff * diff, red) * (1.f / HC);
    out[node * HC + j] = ln_g[j] * diff * rsqrtf(var + LN_EPS) + ln_b[j];
}

// ---------------------------------------------------------------------------
extern "C" void kernel_launch(void* const* d_in, const int* in_sizes, int n_in,
                              void* d_out, int out_size, void* d_ws, size_t ws_size,
                              hipStream_t stream) {
    const float* x       = (const float*)d_in[0];
    const int*   ei      = (const int*)d_in[1];
    const float* W       = (const float*)d_in[2];
    const float* att_src = (const float*)d_in[3];
    const float* att_dst = (const float*)d_in[4];
    const float* bias    = (const float*)d_in[5];
    const float* res_w   = (const float*)d_in[6];
    const float* res_b   = (const float*)d_in[7];
    const float* ln_g    = (const float*)d_in[8];
    const float* ln_b    = (const float*)d_in[9];
    float* out = (float*)d_out;

    int n = in_sizes[0] / F_IN;          // 50000
    int E = in_sizes[1] / 2;             // 800000

    float* ws    = (float*)d_ws;
    float* h     = ws;                               // n*HC
    float* a_src = h     + (size_t)n * HC;           // n*NH
    float* a_dst = a_src + (size_t)n * NH;           // n*NH
    float* denom = a_dst + (size_t)n * NH;           // n*NH
    float* accum = denom + (size_t)n * NH;           // n*HC
    int*   flag  = (int*)(accum + (size_t)n * HC);   // 1

    // zero denom + accum (contiguous)
    hipMemsetAsync(denom, 0, (size_t)n * (NH + HC) * sizeof(float), stream);

    k0_detect<<<1, 256, 0, stream>>>(ei, E, flag);

    k1_node_gemm<<<n, 128, 0, stream>>>(x, W, att_src, att_dst, h, a_src, a_dst);

    int Etot = E + n;
    k2_denom<<<(Etot + 255) / 256, 256, 0, stream>>>(ei, E, n, flag, a_src, a_dst, denom);

    long long total = (long long)Etot * HC;
    int blocks3 = (int)((total + 255) / 256);
    k3_message<<<blocks3, 256, 0, stream>>>(ei, E, n, flag, a_src, a_dst, denom, h, accum);

    k4_final<<<n, 128, 0, stream>>>(accum, x, res_w, res_b, bias, ln_g, ln_b, out);
}

// Round 3
// 545.204 us; speedup vs baseline: 1.3771x; 1.3771x over previous
//
#include <hip/hip_runtime.h>

#define F_IN 64
#define NH 4
#define HC 128
#define NEG_SLOPE 0.2f
#define LN_EPS 1e-5f

// ---------------------------------------------------------------------------
// K0: detect whether edge_index arrived as int64 (little-endian) or int32.
// ---------------------------------------------------------------------------
__global__ void k0_detect(const int* __restrict__ ei, int E, int* __restrict__ flag) {
    __shared__ int any_nz;
    if (threadIdx.x == 0) any_nz = 0;
    __syncthreads();
    long long stride = (2LL * E) / 257;
    long long pos = (long long)(threadIdx.x + 1) * stride;
    int w = ei[pos | 1];                 // odd word: int64 high half (==0) or real int32 index
    if (w != 0) atomicOr(&any_nz, 1);
    __syncthreads();
    if (threadIdx.x == 0) flag[0] = (any_nz == 0) ? 1 : 0;   // 1 => int64
}

// ---------------------------------------------------------------------------
// K1: h = x @ W + attention logits. Block=128 (2 waves), 8 nodes/block,
// W staged once in LDS (32 KB), wave-per-node, 2 channels per lane (float2).
// ---------------------------------------------------------------------------
#define K1_NPB 8
__global__ __launch_bounds__(128) void k1_gemm(
    const float* __restrict__ x, const float* __restrict__ W,
    const float* __restrict__ att_src, const float* __restrict__ att_dst,
    float* __restrict__ h, float* __restrict__ a_s, float* __restrict__ a_d, int n)
{
    __shared__ float Ws[F_IN * HC];
    int tid = threadIdx.x;
    {
        const float4* W4 = (const float4*)W;
        float4* Ws4 = (float4*)Ws;
        for (int i = tid; i < F_IN * HC / 4; i += 128) Ws4[i] = W4[i];
    }
    __syncthreads();
    int wid = tid >> 6, lane = tid & 63;
    int c0 = lane * 2;                   // channels c0, c0+1 (same head)
    int head = c0 >> 5;
    float2 as  = *(const float2*)&att_src[c0];
    float2 adt = *(const float2*)&att_dst[c0];
    for (int u = wid; u < K1_NPB; u += 2) {         // wave-uniform loop
        int node = blockIdx.x * K1_NPB + u;
        if (node >= n) break;
        float xr = x[node * F_IN + lane];            // lane k holds x[node][k]
        float ax = 0.f, ay = 0.f;
#pragma unroll
        for (int k = 0; k < F_IN; ++k) {
            float xk = __shfl(xr, k, 64);
            float2 wv = *(const float2*)&Ws[k * HC + c0];
            ax += xk * wv.x;
            ay += xk * wv.y;
        }
        *(float2*)&h[node * HC + c0] = make_float2(ax, ay);
        float vs = ax * as.x + ay * as.y;
        float vd = ax * adt.x + ay * adt.y;
#pragma unroll
        for (int off = 8; off > 0; off >>= 1) {      // reduce 16 lanes = one head
            vs += __shfl_down(vs, off, 16);
            vd += __shfl_down(vd, off, 16);
        }
        if ((lane & 15) == 0) {
            a_s[node * NH + head] = vs;
            a_d[node * NH + head] = vd;
        }
    }
}

// ---------------------------------------------------------------------------
// K_hist: in-degree histogram over the E real edges (self-loops handled in agg)
// ---------------------------------------------------------------------------
__global__ __launch_bounds__(256) void k_hist(const int* __restrict__ ei, int E,
                                              const int* __restrict__ flag, int* __restrict__ deg)
{
    int idx = blockIdx.x * 256 + threadIdx.x;
    if (idx >= E) return;
    int d = flag[0] ? ei[2 * (E + idx)] : ei[E + idx];
    atomicAdd(&deg[d], 1);
}

// ---------------------------------------------------------------------------
// K_scan: single-block exclusive scan of deg -> offsets (in place) + cursor copy
// ---------------------------------------------------------------------------
__global__ __launch_bounds__(1024) void k_scan(int* __restrict__ arr, int* __restrict__ cursor,
                                               int n, int E)
{
    __shared__ int sums[1024];
    int t = threadIdx.x;
    int per = (n + 1023) >> 10;
    int lo = t * per;
    int hi = min(n, lo + per);
    int s = 0;
    for (int i = lo; i < hi; ++i) s += arr[i];
    sums[t] = s;
    __syncthreads();
    for (int off = 1; off < 1024; off <<= 1) {
        int v = (t >= off) ? sums[t - off] : 0;
        __syncthreads();
        sums[t] += v;
        __syncthreads();
    }
    int run = (t == 0) ? 0 : sums[t - 1];
    for (int i = lo; i < hi; ++i) {
        int dv = arr[i];
        arr[i] = run;
        cursor[i] = run;
        run += dv;
    }
    if (t == 0) arr[n] = E;
}

// ---------------------------------------------------------------------------
// K_scatter: counting-sort edge sources by destination
// ---------------------------------------------------------------------------
__global__ __launch_bounds__(256) void k_scatter(const int* __restrict__ ei, int E,
                                                 const int* __restrict__ flag,
                                                 int* __restrict__ cursor,
                                                 int* __restrict__ src_sorted)
{
    int idx = blockIdx.x * 256 + threadIdx.x;
    if (idx >= E) return;
    int is64 = flag[0];
    int s = is64 ? ei[2 * idx] : ei[idx];
    int d = is64 ? ei[2 * (E + idx)] : ei[E + idx];
    int pos = atomicAdd(&cursor[d], 1);
    src_sorted[pos] = s;
}

// ---------------------------------------------------------------------------
// K_agg: wave-per-dst-node CSR gather + online softmax-weighted sum.
// No atomics. Writes pre-bias aggregate to out (overwritten in place by K4).
// block = 256 = 4 independent waves = 4 nodes.
// ---------------------------------------------------------------------------
__global__ __launch_bounds__(256) void k_agg(
    const int* __restrict__ offsets, const int* __restrict__ src_sorted,
    const float* __restrict__ a_s, const float* __restrict__ a_d,
    const float* __restrict__ h, float* __restrict__ out, int n)
{
    int wid = threadIdx.x >> 6, lane = threadIdx.x & 63;
    int d = blockIdx.x * 4 + wid;
    if (d >= n) return;
    int c0 = lane * 2;
    int head = c0 >> 5;
    float ad = a_d[d * NH + head];
    // self-loop contribution
    float e = a_s[d * NH + head] + ad;
    e = (e >= 0.f) ? e : NEG_SLOPE * e;
    float w = __expf(e);
    float denom = w;
    float2 hv = *(const float2*)&h[d * HC + c0];
    float ax = w * hv.x, ay = w * hv.y;

    int lo = offsets[d], hi = offsets[d + 1];
    int k = lo;
    for (; k + 1 < hi; k += 2) {                     // 2 independent chains
        int s0 = src_sorted[k], s1 = src_sorted[k + 1];
        float e0 = a_s[s0 * NH + head] + ad;
        float e1 = a_s[s1 * NH + head] + ad;
        float2 h0 = *(const float2*)&h[s0 * HC + c0];
        float2 h1 = *(const float2*)&h[s1 * HC + c0];
        e0 = (e0 >= 0.f) ? e0 : NEG_SLOPE * e0;
        e1 = (e1 >= 0.f) ? e1 : NEG_SLOPE * e1;
        float w0 = __expf(e0), w1 = __expf(e1);
        denom += w0 + w1;
        ax += w0 * h0.x + w1 * h1.x;
        ay += w0 * h0.y + w1 * h1.y;
    }
    if (k < hi) {
        int s0 = src_sorted[k];
        float e0 = a_s[s0 * NH + head] + ad;
        float2 h0 = *(const float2*)&h[s0 * HC + c0];
        e0 = (e0 >= 0.f) ? e0 : NEG_SLOPE * e0;
        float w0 = __expf(e0);
        denom += w0;
        ax += w0 * h0.x;
        ay += w0 * h0.y;
    }
    float inv = 1.f / denom;
    *(float2*)&out[d * HC + c0] = make_float2(ax * inv, ay * inv);
}

// ---------------------------------------------------------------------------
// K4: epilogue, in-place on out. res_w staged in LDS, 8 nodes/block,
// wave-per-node, wave-level LN reductions (no LDS reduce, no syncthreads).
// ---------------------------------------------------------------------------
#define K4_NPB 8
__device__ inline float wave_bcast_sum(float v) {
#pragma unroll
    for (int off = 32; off > 0; off >>= 1) v += __shfl_down(v, off, 64);
    return __shfl(v, 0, 64);
}

__global__ __launch_bounds__(128) void k4_final(
    const float* __restrict__ x, const float* __restrict__ res_w,
    const float* __restrict__ res_b, const float* __restrict__ bias,
    const float* __restrict__ ln_g, const float* __restrict__ ln_b,
    float* __restrict__ out, int n)
{
    __shared__ float Ws[F_IN * HC];
    int tid = threadIdx.x;
    {
        const float4* W4 = (const float4*)res_w;
        float4* Ws4 = (float4*)Ws;
        for (int i = tid; i < F_IN * HC / 4; i += 128) Ws4[i] = W4[i];
    }
    __syncthreads();
    int wid = tid >> 6, lane = tid & 63;
    int c0 = lane * 2;
    float2 bi = *(const float2*)&bias[c0];
    float2 rb = *(const float2*)&res_b[c0];
    float2 g  = *(const float2*)&ln_g[c0];
    float2 bb = *(const float2*)&ln_b[c0];
    for (int u = wid; u < K4_NPB; u += 2) {
        int node = blockIdx.x * K4_NPB + u;
        if (node >= n) break;
        float xr = x[node * F_IN + lane];
        float rx = 0.f, ry = 0.f;
#pragma unroll
        for (int k = 0; k < F_IN; ++k) {
            float xk = __shfl(xr, k, 64);
            float2 wv = *(const float2*)&Ws[k * HC + c0];
            rx += xk * wv.x;
            ry += xk * wv.y;
        }
        float2 o = *(const float2*)&out[node * HC + c0];
        float ox = o.x + bi.x, oy = o.y + bi.y;
        ox = (ox > 0.f) ? ox : expm1f(ox);           // ELU
        oy = (oy > 0.f) ? oy : expm1f(oy);
        ox += rx + rb.x;
        oy += ry + rb.y;
        float mean = wave_bcast_sum(ox + oy) * (1.f / HC);
        float dx = ox - mean, dy = oy - mean;
        float var = wave_bcast_sum(dx * dx + dy * dy) * (1.f / HC);
        float rs = rsqrtf(var + LN_EPS);
        *(float2*)&out[node * HC + c0] =
            make_float2(g.x * dx * rs + bb.x, g.y * dy * rs + bb.y);
    }
}

// ---------------------------------------------------------------------------
extern "C" void kernel_launch(void* const* d_in, const int* in_sizes, int n_in,
                              void* d_out, int out_size, void* d_ws, size_t ws_size,
                              hipStream_t stream) {
    const float* x       = (const float*)d_in[0];
    const int*   ei      = (const int*)d_in[1];
    const float* W       = (const float*)d_in[2];
    const float* att_src = (const float*)d_in[3];
    const float* att_dst = (const float*)d_in[4];
    const float* bias    = (const float*)d_in[5];
    const float* res_w   = (const float*)d_in[6];
    const float* res_b   = (const float*)d_in[7];
    const float* ln_g    = (const float*)d_in[8];
    const float* ln_b    = (const float*)d_in[9];
    float* out = (float*)d_out;

    int n = in_sizes[0] / F_IN;          // 50000
    int E = in_sizes[1] / 2;             // 800000

    float* ws      = (float*)d_ws;
    float* h       = ws;                                 // n*HC
    float* a_s     = h + (size_t)n * HC;                 // n*NH
    float* a_d     = a_s + (size_t)n * NH;               // n*NH
    int* offsets   = (int*)(a_d + (size_t)n * NH);       // n+1 (deg -> offsets)
    int* cursor    = offsets + (n + 1);                  // n
    int* srcsorted = cursor + n;                         // E
    int* flag      = srcsorted + E;                      // 1

    hipMemsetAsync(offsets, 0, (size_t)(n + 1) * sizeof(int), stream);

    k0_detect<<<1, 256, 0, stream>>>(ei, E, flag);

    k1_gemm<<<(n + K1_NPB - 1) / K1_NPB, 128, 0, stream>>>(
        x, W, att_src, att_dst, h, a_s, a_d, n);

    k_hist<<<(E + 255) / 256, 256, 0, stream>>>(ei, E, flag, offsets);

    k_scan<<<1, 1024, 0, stream>>>(offsets, cursor, n, E);

    k_scatter<<<(E + 255) / 256, 256, 0, stream>>>(ei, E, flag, cursor, srcsorted);

    k_agg<<<(n + 3) / 4, 256, 0, stream>>>(offsets, srcsorted, a_s, a_d, h, out, n);

    k4_final<<<(n + K4_NPB - 1) / K4_NPB, 128, 0, stream>>>(
        x, res_w, res_b, bias, ln_g, ln_b, out, n);
}

// Round 4
// 383.536 us; speedup vs baseline: 1.9576x; 1.4215x over previous
//
#include <hip/hip_runtime.h>

#define F_IN 64
#define NH 4
#define HC 128
#define NEG_SLOPE 0.2f
#define LN_EPS 1e-5f

// ---------------------------------------------------------------------------
// K0: detect whether edge_index arrived as int64 (little-endian) or int32.
// ---------------------------------------------------------------------------
__global__ void k0_detect(const int* __restrict__ ei, int E, int* __restrict__ flag) {
    __shared__ int any_nz;
    if (threadIdx.x == 0) any_nz = 0;
    __syncthreads();
    long long stride = (2LL * E) / 257;
    long long pos = (long long)(threadIdx.x + 1) * stride;
    int w = ei[pos | 1];
    if (w != 0) atomicOr(&any_nz, 1);
    __syncthreads();
    if (threadIdx.x == 0) flag[0] = (any_nz == 0) ? 1 : 0;   // 1 => int64
}

__device__ inline unsigned bfpack(float a, float b) {
    unsigned ua = __float_as_uint(a), ub = __float_as_uint(b);
    ua = (ua + 0x7fffu + ((ua >> 16) & 1u)) >> 16;           // RNE to bf16
    ub = (ub + 0x7fffu + ((ub >> 16) & 1u)) >> 16;
    return ua | (ub << 16);
}

// ---------------------------------------------------------------------------
// KA: fused dual GEMM: h_bf16 = x@W (rounded), r = x@res_w.
// Block 256 = 16 node-rows(i, 4 nodes each) x 16 col-threads(j, 4 cols each).
// 64-node batch per block; weights staged in halves (32 KB) so LDS = 49.6 KB
// => 3 blocks/CU. Inner loop: pure LDS reads + FMA, no shuffles.
// ---------------------------------------------------------------------------
#define NT 64
#define XS_LD 66   // padded leading dim: bank = (2*node + k) % 32 -> conflict-free
__global__ __launch_bounds__(256) void kA_gemm(
    const float* __restrict__ x, const float* __restrict__ W,
    const float* __restrict__ res_w,
    unsigned int* __restrict__ h_bf, float* __restrict__ r, int n)
{
    __shared__ float Ws[F_IN * HC];      // 32 KB, one weight half at a time
    __shared__ float xs[NT * XS_LD];     // 16.9 KB
    int tid = threadIdx.x;
    int j = tid & 15, i = tid >> 4;
    int nb0 = blockIdx.x * NT;

    // stage x batch (float2 coalesced, clamp OOB reads)
#pragma unroll
    for (int it = 0; it < 8; ++it) {
        int f2 = it * 256 + tid;             // 2048 float2 = 64 nodes x 64 k
        int node = f2 >> 5, k2 = f2 & 31;
        int src = nb0 + node; if (src >= n) src = n - 1;
        float2 v = *(const float2*)&x[src * F_IN + k2 * 2];
        xs[node * XS_LD + k2 * 2]     = v.x;
        xs[node * XS_LD + k2 * 2 + 1] = v.y;
    }

    for (int half = 0; half < 2; ++half) {
        __syncthreads();                     // prior compute done before restage
        {
            const float4* src4 = (const float4*)(half ? res_w : W);
            float4* Ws4 = (float4*)Ws;
            for (int it = tid; it < F_IN * HC / 4; it += 256) Ws4[it] = src4[it];
        }
        __syncthreads();

        for (int cg = 0; cg < 2; ++cg) {
            float acc[4][4];
#pragma unroll
            for (int m = 0; m < 4; ++m)
#pragma unroll
                for (int c = 0; c < 4; ++c) acc[m][c] = 0.f;

            const float* wbase = &Ws[cg * 64 + j * 4];
            const float* xbase = &xs[(i * 4) * XS_LD];
#pragma unroll 8
            for (int k2 = 0; k2 < 32; ++k2) {
                float2 xv0 = *(const float2*)&xbase[0 * XS_LD + 2 * k2];
                float2 xv1 = *(const float2*)&xbase[1 * XS_LD + 2 * k2];
                float2 xv2 = *(const float2*)&xbase[2 * XS_LD + 2 * k2];
                float2 xv3 = *(const float2*)&xbase[3 * XS_LD + 2 * k2];
                float4 w0 = *(const float4*)&wbase[(2 * k2) * HC];
                float4 w1 = *(const float4*)&wbase[(2 * k2 + 1) * HC];
                acc[0][0] += xv0.x * w0.x + xv0.y * w1.x;
                acc[0][1] += xv0.x * w0.y + xv0.y * w1.y;
                acc[0][2] += xv0.x * w0.z + xv0.y * w1.z;
                acc[0][3] += xv0.x * w0.w + xv0.y * w1.w;
                acc[1][0] += xv1.x * w0.x + xv1.y * w1.x;
                acc[1][1] += xv1.x * w0.y + xv1.y * w1.y;
                acc[1][2] += xv1.x * w0.z + xv1.y * w1.z;
                acc[1][3] += xv1.x * w0.w + xv1.y * w1.w;
                acc[2][0] += xv2.x * w0.x + xv2.y * w1.x;
                acc[2][1] += xv2.x * w0.y + xv2.y * w1.y;
                acc[2][2] += xv2.x * w0.z + xv2.y * w1.z;
                acc[2][3] += xv2.x * w0.w + xv2.y * w1.w;
                acc[3][0] += xv3.x * w0.x + xv3.y * w1.x;
                acc[3][1] += xv3.x * w0.y + xv3.y * w1.y;
                acc[3][2] += xv3.x * w0.z + xv3.y * w1.z;
                acc[3][3] += xv3.x * w0.w + xv3.y * w1.w;
            }
#pragma unroll
            for (int m = 0; m < 4; ++m) {
                int node = nb0 + i * 4 + m;
                if (node < n) {
                    if (half == 0) {
                        uint2 p = make_uint2(bfpack(acc[m][0], acc[m][1]),
                                             bfpack(acc[m][2], acc[m][3]));
                        *(uint2*)&h_bf[node * 64 + cg * 32 + j * 2] = p;
                    } else {
                        *(float4*)&r[node * HC + cg * 64 + j * 4] =
                            make_float4(acc[m][0], acc[m][1], acc[m][2], acc[m][3]);
                    }
                }
            }
        }
    }
}

// ---------------------------------------------------------------------------
// KB: attention logits from h_bf. Wave per node (4 nodes per 256-block).
// ---------------------------------------------------------------------------
__global__ __launch_bounds__(256) void kB_logits(
    const unsigned int* __restrict__ h_bf,
    const float* __restrict__ att_src, const float* __restrict__ att_dst,
    float* __restrict__ a_s, float* __restrict__ a_d, int n)
{
    int wv = threadIdx.x >> 6, lane = threadIdx.x & 63;
    int node = blockIdx.x * 4 + wv;
    if (node >= n) return;
    unsigned hv = h_bf[node * 64 + lane];
    float h0 = __uint_as_float(hv << 16);
    float h1 = __uint_as_float(hv & 0xffff0000u);
    int c0 = lane * 2;
    float vs = h0 * att_src[c0] + h1 * att_src[c0 + 1];
    float vd = h0 * att_dst[c0] + h1 * att_dst[c0 + 1];
#pragma unroll
    for (int off = 8; off > 0; off >>= 1) {
        vs += __shfl_down(vs, off, 16);
        vd += __shfl_down(vd, off, 16);
    }
    if ((lane & 15) == 0) {
        int head = lane >> 4;
        a_s[node * NH + head] = vs;
        a_d[node * NH + head] = vd;
    }
}

// ---------------------------------------------------------------------------
// K_hist / K_scan / K_scatter: counting sort of edges by destination
// ---------------------------------------------------------------------------
__global__ __launch_bounds__(256) void k_hist(const int* __restrict__ ei, int E,
                                              const int* __restrict__ flag, int* __restrict__ deg)
{
    int idx = blockIdx.x * 256 + threadIdx.x;
    if (idx >= E) return;
    int d = flag[0] ? ei[2 * (E + idx)] : ei[E + idx];
    atomicAdd(&deg[d], 1);
}

__global__ __launch_bounds__(1024) void k_scan(int* __restrict__ arr, int* __restrict__ cursor,
                                               int n, int E)
{
    __shared__ int sums[1024];
    int t = threadIdx.x;
    int per = (n + 1023) >> 10;
    int lo = t * per;
    int hi = min(n, lo + per);
    int s = 0;
    for (int i = lo; i < hi; ++i) s += arr[i];
    sums[t] = s;
    __syncthreads();
    for (int off = 1; off < 1024; off <<= 1) {
        int v = (t >= off) ? sums[t - off] : 0;
        __syncthreads();
        sums[t] += v;
        __syncthreads();
    }
    int run = (t == 0) ? 0 : sums[t - 1];
    for (int i = lo; i < hi; ++i) {
        int dv = arr[i];
        arr[i] = run;
        cursor[i] = run;
        run += dv;
    }
    if (t == 0) arr[n] = E;
}

__global__ __launch_bounds__(256) void k_scatter(const int* __restrict__ ei, int E,
                                                 const int* __restrict__ flag,
                                                 int* __restrict__ cursor,
                                                 int* __restrict__ src_sorted)
{
    int idx = blockIdx.x * 256 + threadIdx.x;
    if (idx >= E) return;
    int is64 = flag[0];
    int s = is64 ? ei[2 * idx] : ei[idx];
    int d = is64 ? ei[2 * (E + idx)] : ei[E + idx];
    int pos = atomicAdd(&cursor[d], 1);
    src_sorted[pos] = s;
}

// ---------------------------------------------------------------------------
// K_agg: wave-per-dst CSR gather (softmax-weighted sum over bf16 h) FUSED with
// the full epilogue: bias, ELU, +r+res_b, LayerNorm, final store. No atomics.
// ---------------------------------------------------------------------------
__device__ inline float wave_bcast_sum(float v) {
#pragma unroll
    for (int off = 32; off > 0; off >>= 1) v += __shfl_down(v, off, 64);
    return __shfl(v, 0, 64);
}

__global__ __launch_bounds__(256) void k_agg(
    const int* __restrict__ offsets, const int* __restrict__ src_sorted,
    const float* __restrict__ a_s, const float* __restrict__ a_d,
    const unsigned int* __restrict__ h_bf, const float* __restrict__ r,
    const float* __restrict__ bias, const float* __restrict__ res_b,
    const float* __restrict__ ln_g, const float* __restrict__ ln_b,
    float* __restrict__ out, int n)
{
    int wv = threadIdx.x >> 6, lane = threadIdx.x & 63;
    int d = blockIdx.x * 4 + wv;
    if (d >= n) return;
    int c0 = lane * 2, head = lane >> 4;
    float ad = a_d[d * NH + head];

    // self-loop
    float e = a_s[d * NH + head] + ad;
    e = (e >= 0.f) ? e : NEG_SLOPE * e;
    float w = __expf(e);
    float denom = w;
    unsigned hv = h_bf[d * 64 + lane];
    float ax = w * __uint_as_float(hv << 16);
    float ay = w * __uint_as_float(hv & 0xffff0000u);

    int lo = offsets[d], hi = offsets[d + 1];
    int k = lo;
    for (; k + 3 < hi; k += 4) {
        int s0 = src_sorted[k],     s1 = src_sorted[k + 1];
        int s2 = src_sorted[k + 2], s3 = src_sorted[k + 3];
        float e0 = a_s[s0 * NH + head] + ad;
        float e1 = a_s[s1 * NH + head] + ad;
        float e2 = a_s[s2 * NH + head] + ad;
        float e3 = a_s[s3 * NH + head] + ad;
        unsigned v0 = h_bf[s0 * 64 + lane];
        unsigned v1 = h_bf[s1 * 64 + lane];
        unsigned v2 = h_bf[s2 * 64 + lane];
        unsigned v3 = h_bf[s3 * 64 + lane];
        e0 = (e0 >= 0.f) ? e0 : NEG_SLOPE * e0;
        e1 = (e1 >= 0.f) ? e1 : NEG_SLOPE * e1;
        e2 = (e2 >= 0.f) ? e2 : NEG_SLOPE * e2;
        e3 = (e3 >= 0.f) ? e3 : NEG_SLOPE * e3;
        float w0 = __expf(e0), w1 = __expf(e1), w2 = __expf(e2), w3 = __expf(e3);
        denom += (w0 + w1) + (w2 + w3);
        ax += w0 * __uint_as_float(v0 << 16) + w1 * __uint_as_float(v1 << 16);
        ax += w2 * __uint_as_float(v2 << 16) + w3 * __uint_as_float(v3 << 16);
        ay += w0 * __uint_as_float(v0 & 0xffff0000u) + w1 * __uint_as_float(v1 & 0xffff0000u);
        ay += w2 * __uint_as_float(v2 & 0xffff0000u) + w3 * __uint_as_float(v3 & 0xffff0000u);
    }
    for (; k < hi; ++k) {
        int s0 = src_sorted[k];
        float e0 = a_s[s0 * NH + head] + ad;
        unsigned v0 = h_bf[s0 * 64 + lane];
        e0 = (e0 >= 0.f) ? e0 : NEG_SLOPE * e0;
        float w0 = __expf(e0);
        denom += w0;
        ax += w0 * __uint_as_float(v0 << 16);
        ay += w0 * __uint_as_float(v0 & 0xffff0000u);
    }

    float inv = 1.f / denom;
    // fused epilogue
    float ox = ax * inv + bias[c0];
    float oy = ay * inv + bias[c0 + 1];
    ox = (ox > 0.f) ? ox : expm1f(ox);
    oy = (oy > 0.f) ? oy : expm1f(oy);
    float2 rv = *(const float2*)&r[d * HC + c0];
    ox += rv.x + res_b[c0];
    oy += rv.y + res_b[c0 + 1];
    float mean = wave_bcast_sum(ox + oy) * (1.f / HC);
    float dx = ox - mean, dy = oy - mean;
    float var = wave_bcast_sum(dx * dx + dy * dy) * (1.f / HC);
    float rs = rsqrtf(var + LN_EPS);
    *(float2*)&out[d * HC + c0] =
        make_float2(ln_g[c0] * dx * rs + ln_b[c0],
                    ln_g[c0 + 1] * dy * rs + ln_b[c0 + 1]);
}

// ---------------------------------------------------------------------------
extern "C" void kernel_launch(void* const* d_in, const int* in_sizes, int n_in,
                              void* d_out, int out_size, void* d_ws, size_t ws_size,
                              hipStream_t stream) {
    const float* x       = (const float*)d_in[0];
    const int*   ei      = (const int*)d_in[1];
    const float* W       = (const float*)d_in[2];
    const float* att_src = (const float*)d_in[3];
    const float* att_dst = (const float*)d_in[4];
    const float* bias    = (const float*)d_in[5];
    const float* res_w   = (const float*)d_in[6];
    const float* res_b   = (const float*)d_in[7];
    const float* ln_g    = (const float*)d_in[8];
    const float* ln_b    = (const float*)d_in[9];
    float* out = (float*)d_out;

    int n = in_sizes[0] / F_IN;          // 50000
    int E = in_sizes[1] / 2;             // 800000

    float*    r         = (float*)d_ws;                       // n*HC f32
    unsigned* h_bf      = (unsigned*)(r + (size_t)n * HC);    // n*64 dwords (bf16x2)
    float*    a_s       = (float*)(h_bf + (size_t)n * 64);    // n*NH
    float*    a_d       = a_s + (size_t)n * NH;               // n*NH
    int*      offsets   = (int*)(a_d + (size_t)n * NH);       // n+1
    int*      cursor    = offsets + (n + 1);                  // n
    int*      srcsorted = cursor + n;                         // E
    int*      flag      = srcsorted + E;                      // 1

    hipMemsetAsync(offsets, 0, (size_t)(n + 1) * sizeof(int), stream);

    k0_detect<<<1, 256, 0, stream>>>(ei, E, flag);

    kA_gemm<<<(n + NT - 1) / NT, 256, 0, stream>>>(x, W, res_w, h_bf, r, n);

    kB_logits<<<(n + 3) / 4, 256, 0, stream>>>(h_bf, att_src, att_dst, a_s, a_d, n);

    k_hist<<<(E + 255) / 256, 256, 0, stream>>>(ei, E, flag, offsets);

    k_scan<<<1, 1024, 0, stream>>>(offsets, cursor, n, E);

    k_scatter<<<(E + 255) / 256, 256, 0, stream>>>(ei, E, flag, cursor, srcsorted);

    k_agg<<<(n + 3) / 4, 256, 0, stream>>>(offsets, srcsorted, a_s, a_d, h_bf, r,
                                           bias, res_b, ln_g, ln_b, out, n);
}

// Round 5
// 285.410 us; speedup vs baseline: 2.6307x; 1.3438x over previous
//
#include <hip/hip_runtime.h>

#define F_IN 64
#define NH 4
#define HC 128
#define NEG_SLOPE 0.2f
#define LN_EPS 1e-5f

// ---------------------------------------------------------------------------
// K0: detect whether edge_index arrived as int64 (little-endian) or int32.
// ---------------------------------------------------------------------------
__global__ void k0_detect(const int* __restrict__ ei, int E, int* __restrict__ flag) {
    __shared__ int any_nz;
    if (threadIdx.x == 0) any_nz = 0;
    __syncthreads();
    long long stride = (2LL * E) / 257;
    long long pos = (long long)(threadIdx.x + 1) * stride;
    int w = ei[pos | 1];
    if (w != 0) atomicOr(&any_nz, 1);
    __syncthreads();
    if (threadIdx.x == 0) flag[0] = (any_nz == 0) ? 1 : 0;   // 1 => int64
}

__device__ inline unsigned bfpack(float a, float b) {
    unsigned ua = __float_as_uint(a), ub = __float_as_uint(b);
    ua = (ua + 0x7fffu + ((ua >> 16) & 1u)) >> 16;           // RNE to bf16
    ub = (ub + 0x7fffu + ((ub >> 16) & 1u)) >> 16;
    return ua | (ub << 16);
}

// ---------------------------------------------------------------------------
// KA: fused dual GEMM: h_bf16 = x@W (rounded), r = x@res_w, PLUS attention
// logits a_s/a_d computed from the f32 accumulators (8-lane shfl reduce).
// Block 256 = 16 node-rows(i) x 16 col-threads(j); 64 nodes per block.
// ---------------------------------------------------------------------------
#define NT 64
#define XS_LD 66
__global__ __launch_bounds__(256) void kA_gemm(
    const float* __restrict__ x, const float* __restrict__ W,
    const float* __restrict__ res_w,
    const float* __restrict__ att_src, const float* __restrict__ att_dst,
    unsigned int* __restrict__ h_bf, float* __restrict__ r,
    float* __restrict__ a_s, float* __restrict__ a_d, int n)
{
    __shared__ float Ws[F_IN * HC];      // 32 KB, one weight half at a time
    __shared__ float xs[NT * XS_LD];     // 16.9 KB
    int tid = threadIdx.x;
    int j = tid & 15, i = tid >> 4;
    int nb0 = blockIdx.x * NT;

#pragma unroll
    for (int it = 0; it < 8; ++it) {
        int f2 = it * 256 + tid;
        int node = f2 >> 5, k2 = f2 & 31;
        int src = nb0 + node; if (src >= n) src = n - 1;
        float2 v = *(const float2*)&x[src * F_IN + k2 * 2];
        xs[node * XS_LD + k2 * 2]     = v.x;
        xs[node * XS_LD + k2 * 2 + 1] = v.y;
    }

    for (int half = 0; half < 2; ++half) {
        __syncthreads();
        {
            const float4* src4 = (const float4*)(half ? res_w : W);
            float4* Ws4 = (float4*)Ws;
            for (int it = tid; it < F_IN * HC / 4; it += 256) Ws4[it] = src4[it];
        }
        __syncthreads();

        for (int cg = 0; cg < 2; ++cg) {
            float acc[4][4];
#pragma unroll
            for (int m = 0; m < 4; ++m)
#pragma unroll
                for (int c = 0; c < 4; ++c) acc[m][c] = 0.f;

            const float* wbase = &Ws[cg * 64 + j * 4];
            const float* xbase = &xs[(i * 4) * XS_LD];
#pragma unroll 8
            for (int k2 = 0; k2 < 32; ++k2) {
                float2 xv0 = *(const float2*)&xbase[0 * XS_LD + 2 * k2];
                float2 xv1 = *(const float2*)&xbase[1 * XS_LD + 2 * k2];
                float2 xv2 = *(const float2*)&xbase[2 * XS_LD + 2 * k2];
                float2 xv3 = *(const float2*)&xbase[3 * XS_LD + 2 * k2];
                float4 w0 = *(const float4*)&wbase[(2 * k2) * HC];
                float4 w1 = *(const float4*)&wbase[(2 * k2 + 1) * HC];
                acc[0][0] += xv0.x * w0.x + xv0.y * w1.x;
                acc[0][1] += xv0.x * w0.y + xv0.y * w1.y;
                acc[0][2] += xv0.x * w0.z + xv0.y * w1.z;
                acc[0][3] += xv0.x * w0.w + xv0.y * w1.w;
                acc[1][0] += xv1.x * w0.x + xv1.y * w1.x;
                acc[1][1] += xv1.x * w0.y + xv1.y * w1.y;
                acc[1][2] += xv1.x * w0.z + xv1.y * w1.z;
                acc[1][3] += xv1.x * w0.w + xv1.y * w1.w;
                acc[2][0] += xv2.x * w0.x + xv2.y * w1.x;
                acc[2][1] += xv2.x * w0.y + xv2.y * w1.y;
                acc[2][2] += xv2.x * w0.z + xv2.y * w1.z;
                acc[2][3] += xv2.x * w0.w + xv2.y * w1.w;
                acc[3][0] += xv3.x * w0.x + xv3.y * w1.x;
                acc[3][1] += xv3.x * w0.y + xv3.y * w1.y;
                acc[3][2] += xv3.x * w0.z + xv3.y * w1.z;
                acc[3][3] += xv3.x * w0.w + xv3.y * w1.w;
            }

            if (half == 0) {
                // store bf16 h + fused attention logits
                float4 asv = *(const float4*)&att_src[cg * 64 + j * 4];
                float4 adv = *(const float4*)&att_dst[cg * 64 + j * 4];
                int head = cg * 2 + (j >> 3);
#pragma unroll
                for (int m = 0; m < 4; ++m) {
                    int node = nb0 + i * 4 + m;
                    float vs = acc[m][0] * asv.x + acc[m][1] * asv.y
                             + acc[m][2] * asv.z + acc[m][3] * asv.w;
                    float vd = acc[m][0] * adv.x + acc[m][1] * adv.y
                             + acc[m][2] * adv.z + acc[m][3] * adv.w;
                    vs += __shfl_down(vs, 4, 8); vd += __shfl_down(vd, 4, 8);
                    vs += __shfl_down(vs, 2, 8); vd += __shfl_down(vd, 2, 8);
                    vs += __shfl_down(vs, 1, 8); vd += __shfl_down(vd, 1, 8);
                    if (node < n) {
                        if ((j & 7) == 0) {
                            a_s[node * NH + head] = vs;
                            a_d[node * NH + head] = vd;
                        }
                        uint2 p = make_uint2(bfpack(acc[m][0], acc[m][1]),
                                             bfpack(acc[m][2], acc[m][3]));
                        *(uint2*)&h_bf[node * 64 + cg * 32 + j * 2] = p;
                    }
                }
            } else {
#pragma unroll
                for (int m = 0; m < 4; ++m) {
                    int node = nb0 + i * 4 + m;
                    if (node < n)
                        *(float4*)&r[node * HC + cg * 64 + j * 4] =
                            make_float4(acc[m][0], acc[m][1], acc[m][2], acc[m][3]);
                }
            }
        }
    }
}

// ---------------------------------------------------------------------------
// Counting sort: hist -> 3-phase multi-block scan -> scatter
// ---------------------------------------------------------------------------
__global__ __launch_bounds__(256) void k_hist(const int* __restrict__ ei, int E,
                                              const int* __restrict__ flag, int* __restrict__ deg)
{
    int idx = blockIdx.x * 256 + threadIdx.x;
    if (idx >= E) return;
    int d = flag[0] ? ei[2 * (E + idx)] : ei[E + idx];
    atomicAdd(&deg[d], 1);
}

// Phase 1: per-block (256-elem chunk) sums
__global__ __launch_bounds__(256) void k_scan_p1(const int* __restrict__ deg, int n,
                                                 int* __restrict__ bsums)
{
    __shared__ int red[4];
    int i = blockIdx.x * 256 + threadIdx.x;
    int v = (i < n) ? deg[i] : 0;
#pragma unroll
    for (int off = 32; off > 0; off >>= 1) v += __shfl_down(v, off, 64);
    int lane = threadIdx.x & 63, wv = threadIdx.x >> 6;
    if (lane == 0) red[wv] = v;
    __syncthreads();
    if (threadIdx.x == 0)
        bsums[blockIdx.x] = red[0] + red[1] + red[2] + red[3];
}

// Phase 2: single-block exclusive scan over nblk (<=256) block sums, in place
__global__ __launch_bounds__(256) void k_scan_p2(int* __restrict__ bsums, int nblk)
{
    __shared__ int sh[256];
    int t = threadIdx.x;
    int v = (t < nblk) ? bsums[t] : 0;
    sh[t] = v;
    __syncthreads();
#pragma unroll
    for (int off = 1; off < 256; off <<= 1) {
        int u = (t >= off) ? sh[t - off] : 0;
        __syncthreads();
        sh[t] += u;
        __syncthreads();
    }
    if (t < nblk) bsums[t] = sh[t] - v;      // exclusive
}

// Phase 3: per-block exclusive scan + block prefix; writes offsets & cursor
__global__ __launch_bounds__(256) void k_scan_p3(int* __restrict__ deg_off,
                                                 const int* __restrict__ bsums,
                                                 int* __restrict__ cursor, int n, int E)
{
    __shared__ int sh[256];
    int t = threadIdx.x;
    int i = blockIdx.x * 256 + t;
    int v = (i < n) ? deg_off[i] : 0;
    sh[t] = v;
    __syncthreads();
#pragma unroll
    for (int off = 1; off < 256; off <<= 1) {
        int u = (t >= off) ? sh[t - off] : 0;
        __syncthreads();
        sh[t] += u;
        __syncthreads();
    }
    int excl = sh[t] - v + bsums[blockIdx.x];
    if (i < n) { deg_off[i] = excl; cursor[i] = excl; }
    if (blockIdx.x == 0 && t == 0) deg_off[n] = E;
}

__global__ __launch_bounds__(256) void k_scatter(const int* __restrict__ ei, int E,
                                                 const int* __restrict__ flag,
                                                 int* __restrict__ cursor,
                                                 int* __restrict__ src_sorted)
{
    int idx = blockIdx.x * 256 + threadIdx.x;
    if (idx >= E) return;
    int is64 = flag[0];
    int s = is64 ? ei[2 * idx] : ei[idx];
    int d = is64 ? ei[2 * (E + idx)] : ei[E + idx];
    int pos = atomicAdd(&cursor[d], 1);
    src_sorted[pos] = s;
}

// ---------------------------------------------------------------------------
// K_agg: wave-per-dst CSR gather + softmax + full fused epilogue.
// ---------------------------------------------------------------------------
__device__ inline float wave_bcast_sum(float v) {
#pragma unroll
    for (int off = 32; off > 0; off >>= 1) v += __shfl_down(v, off, 64);
    return __shfl(v, 0, 64);
}

__global__ __launch_bounds__(256) void k_agg(
    const int* __restrict__ offsets, const int* __restrict__ src_sorted,
    const float* __restrict__ a_s, const float* __restrict__ a_d,
    const unsigned int* __restrict__ h_bf, const float* __restrict__ r,
    const float* __restrict__ bias, const float* __restrict__ res_b,
    const float* __restrict__ ln_g, const float* __restrict__ ln_b,
    float* __restrict__ out, int n)
{
    int wv = threadIdx.x >> 6, lane = threadIdx.x & 63;
    int d = blockIdx.x * 4 + wv;
    if (d >= n) return;
    int c0 = lane * 2, head = lane >> 4;
    float ad = a_d[d * NH + head];

    float e = a_s[d * NH + head] + ad;
    e = (e >= 0.f) ? e : NEG_SLOPE * e;
    float w = __expf(e);
    float denom = w;
    unsigned hv = h_bf[d * 64 + lane];
    float ax = w * __uint_as_float(hv << 16);
    float ay = w * __uint_as_float(hv & 0xffff0000u);

    int lo = offsets[d], hi = offsets[d + 1];
    int k = lo;
    for (; k + 3 < hi; k += 4) {
        int s0 = src_sorted[k],     s1 = src_sorted[k + 1];
        int s2 = src_sorted[k + 2], s3 = src_sorted[k + 3];
        float e0 = a_s[s0 * NH + head] + ad;
        float e1 = a_s[s1 * NH + head] + ad;
        float e2 = a_s[s2 * NH + head] + ad;
        float e3 = a_s[s3 * NH + head] + ad;
        unsigned v0 = h_bf[s0 * 64 + lane];
        unsigned v1 = h_bf[s1 * 64 + lane];
        unsigned v2 = h_bf[s2 * 64 + lane];
        unsigned v3 = h_bf[s3 * 64 + lane];
        e0 = (e0 >= 0.f) ? e0 : NEG_SLOPE * e0;
        e1 = (e1 >= 0.f) ? e1 : NEG_SLOPE * e1;
        e2 = (e2 >= 0.f) ? e2 : NEG_SLOPE * e2;
        e3 = (e3 >= 0.f) ? e3 : NEG_SLOPE * e3;
        float w0 = __expf(e0), w1 = __expf(e1), w2 = __expf(e2), w3 = __expf(e3);
        denom += (w0 + w1) + (w2 + w3);
        ax += w0 * __uint_as_float(v0 << 16) + w1 * __uint_as_float(v1 << 16);
        ax += w2 * __uint_as_float(v2 << 16) + w3 * __uint_as_float(v3 << 16);
        ay += w0 * __uint_as_float(v0 & 0xffff0000u) + w1 * __uint_as_float(v1 & 0xffff0000u);
        ay += w2 * __uint_as_float(v2 & 0xffff0000u) + w3 * __uint_as_float(v3 & 0xffff0000u);
    }
    for (; k < hi; ++k) {
        int s0 = src_sorted[k];
        float e0 = a_s[s0 * NH + head] + ad;
        unsigned v0 = h_bf[s0 * 64 + lane];
        e0 = (e0 >= 0.f) ? e0 : NEG_SLOPE * e0;
        float w0 = __expf(e0);
        denom += w0;
        ax += w0 * __uint_as_float(v0 << 16);
        ay += w0 * __uint_as_float(v0 & 0xffff0000u);
    }

    float inv = 1.f / denom;
    float ox = ax * inv + bias[c0];
    float oy = ay * inv + bias[c0 + 1];
    ox = (ox > 0.f) ? ox : expm1f(ox);
    oy = (oy > 0.f) ? oy : expm1f(oy);
    float2 rv = *(const float2*)&r[d * HC + c0];
    ox += rv.x + res_b[c0];
    oy += rv.y + res_b[c0 + 1];
    float mean = wave_bcast_sum(ox + oy) * (1.f / HC);
    float dx = ox - mean, dy = oy - mean;
    float var = wave_bcast_sum(dx * dx + dy * dy) * (1.f / HC);
    float rs = rsqrtf(var + LN_EPS);
    *(float2*)&out[d * HC + c0] =
        make_float2(ln_g[c0] * dx * rs + ln_b[c0],
                    ln_g[c0 + 1] * dy * rs + ln_b[c0 + 1]);
}

// ---------------------------------------------------------------------------
extern "C" void kernel_launch(void* const* d_in, const int* in_sizes, int n_in,
                              void* d_out, int out_size, void* d_ws, size_t ws_size,
                              hipStream_t stream) {
    const float* x       = (const float*)d_in[0];
    const int*   ei      = (const int*)d_in[1];
    const float* W       = (const float*)d_in[2];
    const float* att_src = (const float*)d_in[3];
    const float* att_dst = (const float*)d_in[4];
    const float* bias    = (const float*)d_in[5];
    const float* res_w   = (const float*)d_in[6];
    const float* res_b   = (const float*)d_in[7];
    const float* ln_g    = (const float*)d_in[8];
    const float* ln_b    = (const float*)d_in[9];
    float* out = (float*)d_out;

    int n = in_sizes[0] / F_IN;          // 50000
    int E = in_sizes[1] / 2;             // 800000
    int nblk = (n + 255) / 256;          // 196 (must be <= 256)

    float*    r         = (float*)d_ws;                       // n*HC f32
    unsigned* h_bf      = (unsigned*)(r + (size_t)n * HC);    // n*64 dwords
    float*    a_s       = (float*)(h_bf + (size_t)n * 64);    // n*NH
    float*    a_d       = a_s + (size_t)n * NH;               // n*NH
    int*      offsets   = (int*)(a_d + (size_t)n * NH);       // n+1 (deg->offsets)
    int*      cursor    = offsets + (n + 1);                  // n
    int*      bsums     = cursor + n;                         // nblk
    int*      srcsorted = bsums + 256;                        // E
    int*      flag      = srcsorted + E;                      // 1

    hipMemsetAsync(offsets, 0, (size_t)(n + 1) * sizeof(int), stream);

    k0_detect<<<1, 256, 0, stream>>>(ei, E, flag);

    kA_gemm<<<(n + NT - 1) / NT, 256, 0, stream>>>(
        x, W, res_w, att_src, att_dst, h_bf, r, a_s, a_d, n);

    k_hist<<<(E + 255) / 256, 256, 0, stream>>>(ei, E, flag, offsets);

    k_scan_p1<<<nblk, 256, 0, stream>>>(offsets, n, bsums);
    k_scan_p2<<<1, 256, 0, stream>>>(bsums, nblk);
    k_scan_p3<<<nblk, 256, 0, stream>>>(offsets, bsums, cursor, n, E);

    k_scatter<<<(E + 255) / 256, 256, 0, stream>>>(ei, E, flag, cursor, srcsorted);

    k_agg<<<(n + 3) / 4, 256, 0, stream>>>(offsets, srcsorted, a_s, a_d, h_bf, r,
                                           bias, res_b, ln_g, ln_b, out, n);
}